// Round 5
// baseline (416.570 us; speedup 1.0000x reference)
//
#include <hip/hip_runtime.h>

typedef __bf16 bf16x8 __attribute__((ext_vector_type(8)));
typedef __bf16 bf16x4 __attribute__((ext_vector_type(4)));
typedef float  f32x4  __attribute__((ext_vector_type(4)));

#define DEVFN static __device__ __forceinline__

// D = A*B + C ; A = weight fragment, B = data fragment (swapped-operand scheme)
DEVFN f32x4 mfma16(bf16x8 a, bf16x8 b, f32x4 c) {
  return __builtin_amdgcn_mfma_f32_16x16x32_bf16(a, b, c, 0, 0, 0);
}

DEVFN float silu_f(float x) {
  float e = __builtin_amdgcn_exp2f(x * -1.44269504f);
  return x * __builtin_amdgcn_rcpf(1.0f + e);
}

// block DS reordering across this point; VALU/SALU/MFMA/VMEM may cross
DEVFN void sbar() { __builtin_amdgcn_sched_barrier(0x7F); }

DEVFN bf16x8 bzero8() {
  bf16x8 v = {(__bf16)0.f,(__bf16)0.f,(__bf16)0.f,(__bf16)0.f,
              (__bf16)0.f,(__bf16)0.f,(__bf16)0.f,(__bf16)0.f};
  return v;
}
DEVFN f32x4 fzero4() { f32x4 v = {0.f,0.f,0.f,0.f}; return v; }

// ---------------- LDS layout (bytes) ----------------
#define OFF_W2   0u        // 12288 : 4kt x 3nt x 1024
#define OFF_W3   12288u    // 4608  : 3nt x 1024 + 3nt x 512
#define OFF_W4   16896u
#define OFF_W5   21504u
#define OFF_W6   26112u
#define OFF_W7   30720u    // 12288 : 8nt x 1024 + 8nt x 512
#define OFF_BIAS 43008u    // 496 floats (b1[128] b2..b6[48*5] b7[128]) ; 16B-aligned
#define OFF_SCR  45056u    // per-wave scratch: one chunk, 32 rows x 72B (3 blocks/CU fits)
#define SCR_ROW    72u
#define SCR_RT     1152u   // 16 rows * 72
#define SCR_STRIDE 2304u   // 2 row-tiles
#define SMEM_TOTAL 54272u  // <= 163840/3 -> 3 blocks/CU

// pack weights of a K=48 consumer layer into A-frag layout (elem = W[k][n])
DEVFN void init48(unsigned char* smem, unsigned base, const float* W, int Nout, int NT, int tid) {
  for (int t = tid; t < NT*512; t += 256) {           // full frags (k 0..31)
    int i = t & 7, ln = (t >> 3) & 63, nt = t >> 9;
    int k = ((ln >> 4) << 3) + i;
    int n = (nt << 4) + (ln & 15);
    *(__bf16*)(smem + base + 2u*(unsigned)t) = (__bf16)W[k*Nout + n];
  }
  for (int t = tid; t < NT*256; t += 256) {           // half frags (k 32..47), 32-lane pattern
    int i = t & 7, ln = (t >> 3) & 31, nt = t >> 8;
    int k = 32 + ((ln >> 4) << 3) + i;
    int n = (nt << 4) + (ln & 15);
    *(__bf16*)(smem + base + (unsigned)(NT*1024) + 2u*(unsigned)t) = (__bf16)W[k*Nout + n];
  }
}

// bias C-init fragment: lane (g) -> {b[nt*16+4g+r]} r=0..3 (16B-aligned b128 read)
DEVFN f32x4 biasFrag(const float* sB, int off, int nt, int g) {
  return *(const f32x4*)(sB + off + nt*16 + 4*g);
}

// packed activation write: lane owns D[n=4g+r][m=colId] -> 4 k-contiguous bf16 in row colId
DEVFN void writeTile(unsigned char* sw, f32x4 t0, f32x4 t1, int slot, unsigned wBaseW) {
  bf16x4 p0, p1;
#pragma unroll
  for (int r = 0; r < 4; ++r) {
    p0[r] = (__bf16)silu_f(t0[r]);
    p1[r] = (__bf16)silu_f(t1[r]);
  }
  *(bf16x4*)(sw + wBaseW + (unsigned)slot*32u)           = p0;
  *(bf16x4*)(sw + SCR_RT + wBaseW + (unsigned)slot*32u)  = p1;
}

DEVFN void readA(const unsigned char* sw, unsigned aBase, bf16x8 (&af)[2]) {
  af[0] = *(const bf16x8*)(sw + aBase);
  af[1] = *(const bf16x8*)(sw + SCR_RT + aBase);
}

template<int NTO>
DEVFN void consumeFull(const unsigned char* smem, unsigned fragBase, unsigned bOff,
                       const bf16x8 (&af)[2], f32x4 (&acc)[2][NTO]) {
#pragma unroll
  for (int nt = 0; nt < NTO; ++nt) {
    bf16x8 w = *(const bf16x8*)(smem + fragBase + (unsigned)nt*1024u + bOff);
    acc[0][nt] = mfma16(w, af[0], acc[0][nt]);
    acc[1][nt] = mfma16(w, af[1], acc[1][nt]);
  }
}

template<int NTO>
DEVFN void consumeHalf(const unsigned char* smem, unsigned halfBase, unsigned hOff,
                       const bf16x8 (&af)[2], f32x4 (&acc)[2][NTO]) {
#pragma unroll
  for (int nt = 0; nt < NTO; ++nt) {
    bf16x8 w = *(const bf16x8*)(smem + halfBase + (unsigned)nt*512u + hOff);
    acc[0][nt] = mfma16(w, af[0], acc[0][nt]);
    acc[1][nt] = mfma16(w, af[1], acc[1][nt]);
  }
}

// stream a 48-wide producer acc (3 ntiles, bias pre-added) into consumer acc (bias pre-init'd)
DEVFN void stream48(unsigned char* sw, unsigned char* smem,
                    unsigned wfragBase, const f32x4 (&accP)[2][3], f32x4 (&accO)[2][3],
                    unsigned wBaseW, unsigned aBase, unsigned bOff,
                    unsigned hOff, unsigned zOff) {
  bf16x8 af[2];
  // chunk kt0: k 0..31 (ntiles 0,1)
  sbar();
  writeTile(sw, accP[0][0], accP[1][0], 0, wBaseW);
  writeTile(sw, accP[0][1], accP[1][1], 1, wBaseW);
  sbar();
  readA(sw, aBase, af);
  consumeFull<3>(smem, wfragBase, bOff, af, accO);
  // chunk kt1: k 32..47 real (ntile 2) + zero cols 16..31 of chunk
  sbar();
  *(unsigned long long*)(sw + zOff)      = 0ull;
  *(unsigned long long*)(sw + zOff + 8u) = 0ull;
  writeTile(sw, accP[0][2], accP[1][2], 0, wBaseW);
  sbar();
  readA(sw, aBase, af);
  consumeHalf<3>(smem, wfragBase + 3u*1024u, hOff, af, accO);
}

DEVFN void loadIn(const float* __restrict__ dims, const float* __restrict__ xyz,
                  int grp, int lane, int N, float (&buf)[2][6]) {
#pragma unroll
  for (int rt = 0; rt < 2; ++rt)
#pragma unroll
    for (int j = 0; j < 6; ++j) buf[rt][j] = 0.f;
  if (lane < 16) {
#pragma unroll
    for (int rt = 0; rt < 2; ++rt) {
      int row = grp*32 + rt*16 + lane;
      if (row < N) {
        const float* dp = dims + (size_t)row*3u;
        const float* xp = xyz  + (size_t)row*3u;
        buf[rt][0] = dp[0]; buf[rt][1] = dp[1]; buf[rt][2] = dp[2];
        buf[rt][3] = xp[0]; buf[rt][4] = xp[1]; buf[rt][5] = xp[2];
      }
    }
  }
}

__global__ void __launch_bounds__(256, 3)
pinn_mlp_kernel(const float* __restrict__ dims, const float* __restrict__ xyz,
                const float* __restrict__ W1, const float* __restrict__ b1,
                const float* __restrict__ W2, const float* __restrict__ b2,
                const float* __restrict__ W3, const float* __restrict__ b3,
                const float* __restrict__ W4, const float* __restrict__ b4,
                const float* __restrict__ W5, const float* __restrict__ b5,
                const float* __restrict__ W6, const float* __restrict__ b6,
                const float* __restrict__ W7, const float* __restrict__ b7,
                const float* __restrict__ W8, const float* __restrict__ b8,
                float* __restrict__ out, int N) {
  __shared__ __align__(16) unsigned char smem[SMEM_TOTAL];
  const int tid  = threadIdx.x;
  const int lane = tid & 63;
  const int wave = tid >> 6;

  // ---------------- weight / bias packing (once per block) ----------------
  for (int t = tid; t < 6144; t += 256) {   // W2 frags: K=128, 4kt x 3nt
    int i = t & 7, ln = (t >> 3) & 63, f = t >> 9;
    int kt = f / 3, nt = f - kt*3;
    int k = kt*32 + ((ln >> 4) << 3) + i;
    int n = (nt << 4) + (ln & 15);
    *(__bf16*)(smem + OFF_W2 + 2u*(unsigned)t) = (__bf16)W2[k*48 + n];
  }
  init48(smem, OFF_W3, W3, 48, 3, tid);
  init48(smem, OFF_W4, W4, 48, 3, tid);
  init48(smem, OFF_W5, W5, 48, 3, tid);
  init48(smem, OFF_W6, W6, 48, 3, tid);
  init48(smem, OFF_W7, W7, 128, 8, tid);
  float* sB = (float*)(smem + OFF_BIAS);
  for (int t = tid; t < 496; t += 256) {
    float v;
    if      (t < 128) v = b1[t];
    else if (t < 176) v = b2[t - 128];
    else if (t < 224) v = b3[t - 176];
    else if (t < 272) v = b4[t - 224];
    else if (t < 320) v = b5[t - 272];
    else if (t < 368) v = b6[t - 320];
    else              v = b7[t - 368];
    sB[t] = v;
  }

  // persistent register fragments (A-operand layouts)
  bf16x8 w1f[8];
#pragma unroll
  for (int nt = 0; nt < 8; ++nt) w1f[nt] = bzero8();
  if (lane < 16) {
#pragma unroll
    for (int nt = 0; nt < 8; ++nt)
#pragma unroll
      for (int i = 0; i < 6; ++i)
        w1f[nt][i] = (__bf16)W1[i*128 + nt*16 + lane];
  }
  bf16x8 w8f[4];
#pragma unroll
  for (int kt = 0; kt < 4; ++kt) {
    w8f[kt] = bzero8();
    int n = lane & 15;
    if (n < 3) {
#pragma unroll
      for (int i = 0; i < 8; ++i) {
        int k = kt*32 + ((lane >> 4) << 3) + i;
        w8f[kt][i] = (__bf16)W8[k*3 + n];
      }
    }
  }

  __syncthreads();

  // ---------------- per-wave constants ----------------
  const int colId = lane & 15;
  const int g     = lane >> 4;
  unsigned char* sw = smem + OFF_SCR + (unsigned)wave * SCR_STRIDE;
  const unsigned aBase  = (unsigned)colId*SCR_ROW + (unsigned)g*16u;  // data B-frag read base
  const unsigned wBaseW = (unsigned)colId*SCR_ROW + (unsigned)g*8u;   // packed D write base
  const unsigned bOff   = (unsigned)lane*16u;                         // full W-frag lane offset
  const unsigned hOff   = (unsigned)(lane & 31)*16u;                  // half W-frag lane offset
  const unsigned zOff   = (unsigned)(lane >> 1)*SCR_ROW + 32u + (unsigned)(lane & 1)*16u;

  f32x4 b8v = fzero4();
  if (g == 0) { b8v[0] = b8[0]; b8v[1] = b8[1]; b8v[2] = b8[2]; }

  const int nGroups  = (N + 31) >> 5;
  const int gw0      = blockIdx.x*4 + wave;
  const int gwStride = gridDim.x*4;

  float inC[2][6], inN[2][6];
  loadIn(dims, xyz, gw0, lane, N, inC);

  for (int grp = gw0; grp < nGroups; grp += gwStride) {
    const int base = grp * 32;

    // L1 data B operands (rows in regs; lanes>=16 zero)
    bf16x8 a1[2] = {bzero8(), bzero8()};
    if (lane < 16) {
#pragma unroll
      for (int rt = 0; rt < 2; ++rt)
#pragma unroll
        for (int j = 0; j < 6; ++j) a1[rt][j] = (__bf16)inC[rt][j];
    }
    loadIn(dims, xyz, grp + gwStride, lane, N, inN);

    // ---- Stage A: L1 lazily per chunk -> L2 acc (bias-init'd with b2) ----
    f32x4 accA[2][3], accB[2][3];
#pragma unroll
    for (int b = 0; b < 3; ++b) {
      f32x4 bi = biasFrag(sB, 128, b, g);
      accA[0][b] = bi; accA[1][b] = bi;
    }
#pragma unroll
    for (int kt = 0; kt < 4; ++kt) {
      sbar();
#pragma unroll
      for (int c = 0; c < 2; ++c) {
        int nt = 2*kt + c;
        f32x4 bi = biasFrag(sB, 0, nt, g);       // b1
        f32x4 t0 = mfma16(w1f[nt], a1[0], bi);
        f32x4 t1 = mfma16(w1f[nt], a1[1], bi);
        writeTile(sw, t0, t1, c, wBaseW);
      }
      sbar();
      bf16x8 af[2]; readA(sw, aBase, af);
      consumeFull<3>(smem, OFF_W2 + (unsigned)kt*3072u, bOff, af, accA);
    }

    // ---- Stage B: 48-wide chain, ping-pong accs, consumer bias pre-init ----
#pragma unroll
    for (int b = 0; b < 3; ++b) { f32x4 bi = biasFrag(sB, 176, b, g); accB[0][b] = bi; accB[1][b] = bi; }
    stream48(sw, smem, OFF_W3, accA, accB, wBaseW, aBase, bOff, hOff, zOff);
#pragma unroll
    for (int b = 0; b < 3; ++b) { f32x4 bi = biasFrag(sB, 224, b, g); accA[0][b] = bi; accA[1][b] = bi; }
    stream48(sw, smem, OFF_W4, accB, accA, wBaseW, aBase, bOff, hOff, zOff);
#pragma unroll
    for (int b = 0; b < 3; ++b) { f32x4 bi = biasFrag(sB, 272, b, g); accB[0][b] = bi; accB[1][b] = bi; }
    stream48(sw, smem, OFF_W5, accA, accB, wBaseW, aBase, bOff, hOff, zOff);
#pragma unroll
    for (int b = 0; b < 3; ++b) { f32x4 bi = biasFrag(sB, 320, b, g); accA[0][b] = bi; accA[1][b] = bi; }
    stream48(sw, smem, OFF_W6, accB, accA, wBaseW, aBase, bOff, hOff, zOff);
    // accA now holds L6 pre-activation (b6 included)

    // ---- Stage C: fused L6 -> L7 -> L8 ----
    sbar();
    writeTile(sw, accA[0][0], accA[1][0], 0, wBaseW);
    writeTile(sw, accA[0][1], accA[1][1], 1, wBaseW);
    sbar();
    bf16x8 af0[2]; readA(sw, aBase, af0);
    sbar();
    *(unsigned long long*)(sw + zOff)      = 0ull;
    *(unsigned long long*)(sw + zOff + 8u) = 0ull;
    writeTile(sw, accA[0][2], accA[1][2], 0, wBaseW);
    sbar();
    bf16x8 af1[2]; readA(sw, aBase, af1);

    f32x4 acc8[2] = {b8v, b8v};
#pragma unroll
    for (int kt = 0; kt < 4; ++kt) {
      sbar();
#pragma unroll
      for (int c = 0; c < 2; ++c) {
        int nt = 2*kt + c;
        bf16x8 wfull = *(const bf16x8*)(smem + OFF_W7 + (unsigned)nt*1024u + bOff);
        bf16x8 whalf = *(const bf16x8*)(smem + OFF_W7 + 8192u + (unsigned)nt*512u + hOff);
        f32x4 bi = biasFrag(sB, 368, nt, g);     // b7
        f32x4 t0 = mfma16(whalf, af1[0], mfma16(wfull, af0[0], bi));
        f32x4 t1 = mfma16(whalf, af1[1], mfma16(wfull, af0[1], bi));
        writeTile(sw, t0, t1, c, wBaseW);
      }
      sbar();
      bf16x8 af8[2]; readA(sw, aBase, af8);
      acc8[0] = mfma16(w8f[kt], af8[0], acc8[0]);
      acc8[1] = mfma16(w8f[kt], af8[1], acc8[1]);
    }

    // ---- store fp32 output: lane (g==0, colId) owns row base+rt*16+colId, 3 floats ----
    if (g == 0) {
#pragma unroll
      for (int rt = 0; rt < 2; ++rt) {
        int row = base + rt*16 + colId;
        if (row < N) {
          size_t o = (size_t)row*3u;
          out[o+0] = acc8[rt][0];
          out[o+1] = acc8[rt][1];
          out[o+2] = acc8[rt][2];
        }
      }
    }

    // rotate prefetched inputs
#pragma unroll
    for (int rt = 0; rt < 2; ++rt)
#pragma unroll
      for (int j = 0; j < 6; ++j) inC[rt][j] = inN[rt][j];
  }
}

extern "C" void kernel_launch(void* const* d_in, const int* in_sizes, int n_in,
                              void* d_out, int out_size, void* d_ws, size_t ws_size,
                              hipStream_t stream) {
  const float* dims = (const float*)d_in[0];
  const float* xyz  = (const float*)d_in[1];
  const float* W1 = (const float*)d_in[2];  const float* b1 = (const float*)d_in[3];
  const float* W2 = (const float*)d_in[4];  const float* b2 = (const float*)d_in[5];
  const float* W3 = (const float*)d_in[6];  const float* b3 = (const float*)d_in[7];
  const float* W4 = (const float*)d_in[8];  const float* b4 = (const float*)d_in[9];
  const float* W5 = (const float*)d_in[10]; const float* b5 = (const float*)d_in[11];
  const float* W6 = (const float*)d_in[12]; const float* b6 = (const float*)d_in[13];
  const float* W7 = (const float*)d_in[14]; const float* b7 = (const float*)d_in[15];
  const float* W8 = (const float*)d_in[16]; const float* b8 = (const float*)d_in[17];
  float* out = (float*)d_out;
  const int N = in_sizes[0] / 3;

  pinn_mlp_kernel<<<dim3(768), dim3(256), 0, stream>>>(
      dims, xyz, W1, b1, W2, b2, W3, b3, W4, b4, W5, b5, W6, b6, W7, b7, W8, b8,
      out, N);
}

// Round 6
// 298.211 us; speedup vs baseline: 1.3969x; 1.3969x over previous
//
#include <hip/hip_runtime.h>

typedef __bf16 bf16x8 __attribute__((ext_vector_type(8)));
typedef __bf16 bf16x4 __attribute__((ext_vector_type(4)));
typedef float  f32x4  __attribute__((ext_vector_type(4)));

#define DEVFN static __device__ __forceinline__

// D = A*B + C ; A = weight fragment, B = data fragment (swapped-operand scheme)
DEVFN f32x4 mfma16(bf16x8 a, bf16x8 b, f32x4 c) {
  return __builtin_amdgcn_mfma_f32_16x16x32_bf16(a, b, c, 0, 0, 0);
}

DEVFN float silu_f(float x) {
  float e = __builtin_amdgcn_exp2f(x * -1.44269504f);
  return x * __builtin_amdgcn_rcpf(1.0f + e);
}

// block DS reordering across this point; VALU/SALU/MFMA/VMEM may cross
DEVFN void sbar() { __builtin_amdgcn_sched_barrier(0x7F); }

DEVFN bf16x8 bzero8() {
  bf16x8 v = {(__bf16)0.f,(__bf16)0.f,(__bf16)0.f,(__bf16)0.f,
              (__bf16)0.f,(__bf16)0.f,(__bf16)0.f,(__bf16)0.f};
  return v;
}
DEVFN f32x4 fzero4() { f32x4 v = {0.f,0.f,0.f,0.f}; return v; }

// ---------------- LDS layout (bytes) ----------------
// SCR_ROW = 80: 16B-aligned b128 reads for every colId (80*colId % 16 == 0)
// AND 20-bank row stride (good spread). 72 broke alignment (round-5 regression).
#define OFF_W2   0u        // 12288 : 4kt x 3nt x 1024
#define OFF_W3   12288u    // 4608  : 3nt x 1024 + 3nt x 512
#define OFF_W4   16896u
#define OFF_W5   21504u
#define OFF_W6   26112u
#define OFF_W7   30720u    // 12288 : 8nt x 1024 + 8nt x 512
#define OFF_BIAS 43008u    // 496 floats (b1[128] b2..b6[48*5] b7[128]), 1984 B
#define OFF_SCR  44992u    // per-wave scratch: one chunk, 32 rows x 80B
#define SCR_ROW    80u
#define SCR_RT     1280u   // 16 rows * 80
#define SCR_STRIDE 2560u   // 2 row-tiles
#define NWAVES   8
#define BLOCK    512
#define SMEM_TOTAL 65472u  // 44992 + 8*2560 ; <= 64KiB, 2 blocks/CU -> 16 waves/CU

// pack weights of a K=48 consumer layer into A-frag layout (elem = W[k][n])
DEVFN void init48(unsigned char* smem, unsigned base, const float* W, int Nout, int NT, int tid) {
  for (int t = tid; t < NT*512; t += BLOCK) {          // full frags (k 0..31)
    int i = t & 7, ln = (t >> 3) & 63, nt = t >> 9;
    int k = ((ln >> 4) << 3) + i;
    int n = (nt << 4) + (ln & 15);
    *(__bf16*)(smem + base + 2u*(unsigned)t) = (__bf16)W[k*Nout + n];
  }
  for (int t = tid; t < NT*256; t += BLOCK) {          // half frags (k 32..47), 32-lane pattern
    int i = t & 7, ln = (t >> 3) & 31, nt = t >> 8;
    int k = 32 + ((ln >> 4) << 3) + i;
    int n = (nt << 4) + (ln & 15);
    *(__bf16*)(smem + base + (unsigned)(NT*1024) + 2u*(unsigned)t) = (__bf16)W[k*Nout + n];
  }
}

// bias C-init fragment: lane (g) -> {b[nt*16+4g+r]} r=0..3 (16B-aligned b128 read)
DEVFN f32x4 biasFrag(const float* sB, int off, int nt, int g) {
  return *(const f32x4*)(sB + off + nt*16 + 4*g);
}

// packed activation write: lane owns D[n=4g+r][m=colId] -> 4 k-contiguous bf16 in row colId
DEVFN void writeTile(unsigned char* sw, f32x4 t0, f32x4 t1, int slot, unsigned wBaseW) {
  bf16x4 p0, p1;
#pragma unroll
  for (int r = 0; r < 4; ++r) {
    p0[r] = (__bf16)silu_f(t0[r]);
    p1[r] = (__bf16)silu_f(t1[r]);
  }
  *(bf16x4*)(sw + wBaseW + (unsigned)slot*32u)           = p0;
  *(bf16x4*)(sw + SCR_RT + wBaseW + (unsigned)slot*32u)  = p1;
}

DEVFN void readA(const unsigned char* sw, unsigned aBase, bf16x8 (&af)[2]) {
  af[0] = *(const bf16x8*)(sw + aBase);
  af[1] = *(const bf16x8*)(sw + SCR_RT + aBase);
}

template<int NTO>
DEVFN void consumeFull(const unsigned char* smem, unsigned fragBase, unsigned bOff,
                       const bf16x8 (&af)[2], f32x4 (&acc)[2][NTO]) {
#pragma unroll
  for (int nt = 0; nt < NTO; ++nt) {
    bf16x8 w = *(const bf16x8*)(smem + fragBase + (unsigned)nt*1024u + bOff);
    acc[0][nt] = mfma16(w, af[0], acc[0][nt]);
    acc[1][nt] = mfma16(w, af[1], acc[1][nt]);
  }
}

template<int NTO>
DEVFN void consumeHalf(const unsigned char* smem, unsigned halfBase, unsigned hOff,
                       const bf16x8 (&af)[2], f32x4 (&acc)[2][NTO]) {
#pragma unroll
  for (int nt = 0; nt < NTO; ++nt) {
    bf16x8 w = *(const bf16x8*)(smem + halfBase + (unsigned)nt*512u + hOff);
    acc[0][nt] = mfma16(w, af[0], acc[0][nt]);
    acc[1][nt] = mfma16(w, af[1], acc[1][nt]);
  }
}

// stream a 48-wide producer acc (3 ntiles, bias pre-added) into consumer acc (bias pre-init'd)
DEVFN void stream48(unsigned char* sw, unsigned char* smem,
                    unsigned wfragBase, const f32x4 (&accP)[2][3], f32x4 (&accO)[2][3],
                    unsigned wBaseW, unsigned aBase, unsigned bOff,
                    unsigned hOff, unsigned zOff) {
  bf16x8 af[2];
  // chunk kt0: k 0..31 (ntiles 0,1)
  sbar();
  writeTile(sw, accP[0][0], accP[1][0], 0, wBaseW);
  writeTile(sw, accP[0][1], accP[1][1], 1, wBaseW);
  sbar();
  readA(sw, aBase, af);
  consumeFull<3>(smem, wfragBase, bOff, af, accO);
  // chunk kt1: k 32..47 real (ntile 2) + zero cols 16..31 of chunk
  sbar();
  *(unsigned long long*)(sw + zOff)      = 0ull;
  *(unsigned long long*)(sw + zOff + 8u) = 0ull;
  writeTile(sw, accP[0][2], accP[1][2], 0, wBaseW);
  sbar();
  readA(sw, aBase, af);
  consumeHalf<3>(smem, wfragBase + 3u*1024u, hOff, af, accO);
}

DEVFN void loadIn(const float* __restrict__ dims, const float* __restrict__ xyz,
                  int grp, int lane, int N, float (&buf)[2][6]) {
#pragma unroll
  for (int rt = 0; rt < 2; ++rt)
#pragma unroll
    for (int j = 0; j < 6; ++j) buf[rt][j] = 0.f;
  if (lane < 16) {
#pragma unroll
    for (int rt = 0; rt < 2; ++rt) {
      int row = grp*32 + rt*16 + lane;
      if (row < N) {
        const float* dp = dims + (size_t)row*3u;
        const float* xp = xyz  + (size_t)row*3u;
        buf[rt][0] = dp[0]; buf[rt][1] = dp[1]; buf[rt][2] = dp[2];
        buf[rt][3] = xp[0]; buf[rt][4] = xp[1]; buf[rt][5] = xp[2];
      }
    }
  }
}

__global__ void __launch_bounds__(BLOCK, 4)
pinn_mlp_kernel(const float* __restrict__ dims, const float* __restrict__ xyz,
                const float* __restrict__ W1, const float* __restrict__ b1,
                const float* __restrict__ W2, const float* __restrict__ b2,
                const float* __restrict__ W3, const float* __restrict__ b3,
                const float* __restrict__ W4, const float* __restrict__ b4,
                const float* __restrict__ W5, const float* __restrict__ b5,
                const float* __restrict__ W6, const float* __restrict__ b6,
                const float* __restrict__ W7, const float* __restrict__ b7,
                const float* __restrict__ W8, const float* __restrict__ b8,
                float* __restrict__ out, int N) {
  __shared__ __align__(16) unsigned char smem[SMEM_TOTAL];
  const int tid  = threadIdx.x;
  const int lane = tid & 63;
  const int wave = tid >> 6;

  // ---------------- weight / bias packing (once per block, 8 waves share) ----------------
  for (int t = tid; t < 6144; t += BLOCK) {   // W2 frags: K=128, 4kt x 3nt
    int i = t & 7, ln = (t >> 3) & 63, f = t >> 9;
    int kt = f / 3, nt = f - kt*3;
    int k = kt*32 + ((ln >> 4) << 3) + i;
    int n = (nt << 4) + (ln & 15);
    *(__bf16*)(smem + OFF_W2 + 2u*(unsigned)t) = (__bf16)W2[k*48 + n];
  }
  init48(smem, OFF_W3, W3, 48, 3, tid);
  init48(smem, OFF_W4, W4, 48, 3, tid);
  init48(smem, OFF_W5, W5, 48, 3, tid);
  init48(smem, OFF_W6, W6, 48, 3, tid);
  init48(smem, OFF_W7, W7, 128, 8, tid);
  float* sB = (float*)(smem + OFF_BIAS);
  for (int t = tid; t < 496; t += BLOCK) {
    float v;
    if      (t < 128) v = b1[t];
    else if (t < 176) v = b2[t - 128];
    else if (t < 224) v = b3[t - 176];
    else if (t < 272) v = b4[t - 224];
    else if (t < 320) v = b5[t - 272];
    else if (t < 368) v = b6[t - 320];
    else              v = b7[t - 368];
    sB[t] = v;
  }

  // persistent register fragments (A-operand layouts)
  bf16x8 w1f[8];
#pragma unroll
  for (int nt = 0; nt < 8; ++nt) w1f[nt] = bzero8();
  if (lane < 16) {
#pragma unroll
    for (int nt = 0; nt < 8; ++nt)
#pragma unroll
      for (int i = 0; i < 6; ++i)
        w1f[nt][i] = (__bf16)W1[i*128 + nt*16 + lane];
  }
  bf16x8 w8f[4];
#pragma unroll
  for (int kt = 0; kt < 4; ++kt) {
    w8f[kt] = bzero8();
    int n = lane & 15;
    if (n < 3) {
#pragma unroll
      for (int i = 0; i < 8; ++i) {
        int k = kt*32 + ((lane >> 4) << 3) + i;
        w8f[kt][i] = (__bf16)W8[k*3 + n];
      }
    }
  }

  __syncthreads();

  // ---------------- per-wave constants ----------------
  const int colId = lane & 15;
  const int g     = lane >> 4;
  unsigned char* sw = smem + OFF_SCR + (unsigned)wave * SCR_STRIDE;
  const unsigned aBase  = (unsigned)colId*SCR_ROW + (unsigned)g*16u;  // data B-frag read base (16B-aligned)
  const unsigned wBaseW = (unsigned)colId*SCR_ROW + (unsigned)g*8u;   // packed D write base
  const unsigned bOff   = (unsigned)lane*16u;                         // full W-frag lane offset
  const unsigned hOff   = (unsigned)(lane & 31)*16u;                  // half W-frag lane offset
  const unsigned zOff   = (unsigned)(lane >> 1)*SCR_ROW + 32u + (unsigned)(lane & 1)*16u;

  f32x4 b8v = fzero4();
  if (g == 0) { b8v[0] = b8[0]; b8v[1] = b8[1]; b8v[2] = b8[2]; }

  const int nGroups  = (N + 31) >> 5;
  const int gw0      = blockIdx.x*NWAVES + wave;
  const int gwStride = gridDim.x*NWAVES;

  float inC[2][6], inN[2][6];
  loadIn(dims, xyz, gw0, lane, N, inC);

  for (int grp = gw0; grp < nGroups; grp += gwStride) {
    const int base = grp * 32;

    // L1 data B operands (rows in regs; lanes>=16 zero)
    bf16x8 a1[2] = {bzero8(), bzero8()};
    if (lane < 16) {
#pragma unroll
      for (int rt = 0; rt < 2; ++rt)
#pragma unroll
        for (int j = 0; j < 6; ++j) a1[rt][j] = (__bf16)inC[rt][j];
    }
    loadIn(dims, xyz, grp + gwStride, lane, N, inN);

    // ---- Stage A: L1 lazily per chunk -> L2 acc (bias-init'd with b2) ----
    f32x4 accA[2][3], accB[2][3];
#pragma unroll
    for (int b = 0; b < 3; ++b) {
      f32x4 bi = biasFrag(sB, 128, b, g);
      accA[0][b] = bi; accA[1][b] = bi;
    }
#pragma unroll
    for (int kt = 0; kt < 4; ++kt) {
      sbar();
#pragma unroll
      for (int c = 0; c < 2; ++c) {
        int nt = 2*kt + c;
        f32x4 bi = biasFrag(sB, 0, nt, g);       // b1
        f32x4 t0 = mfma16(w1f[nt], a1[0], bi);
        f32x4 t1 = mfma16(w1f[nt], a1[1], bi);
        writeTile(sw, t0, t1, c, wBaseW);
      }
      sbar();
      bf16x8 af[2]; readA(sw, aBase, af);
      consumeFull<3>(smem, OFF_W2 + (unsigned)kt*3072u, bOff, af, accA);
    }

    // ---- Stage B: 48-wide chain, ping-pong accs, consumer bias pre-init ----
#pragma unroll
    for (int b = 0; b < 3; ++b) { f32x4 bi = biasFrag(sB, 176, b, g); accB[0][b] = bi; accB[1][b] = bi; }
    stream48(sw, smem, OFF_W3, accA, accB, wBaseW, aBase, bOff, hOff, zOff);
#pragma unroll
    for (int b = 0; b < 3; ++b) { f32x4 bi = biasFrag(sB, 224, b, g); accA[0][b] = bi; accA[1][b] = bi; }
    stream48(sw, smem, OFF_W4, accB, accA, wBaseW, aBase, bOff, hOff, zOff);
#pragma unroll
    for (int b = 0; b < 3; ++b) { f32x4 bi = biasFrag(sB, 272, b, g); accB[0][b] = bi; accB[1][b] = bi; }
    stream48(sw, smem, OFF_W5, accA, accB, wBaseW, aBase, bOff, hOff, zOff);
#pragma unroll
    for (int b = 0; b < 3; ++b) { f32x4 bi = biasFrag(sB, 320, b, g); accA[0][b] = bi; accA[1][b] = bi; }
    stream48(sw, smem, OFF_W6, accB, accA, wBaseW, aBase, bOff, hOff, zOff);
    // accA now holds L6 pre-activation (b6 included)

    // ---- Stage C: fused L6 -> L7 -> L8 ----
    sbar();
    writeTile(sw, accA[0][0], accA[1][0], 0, wBaseW);
    writeTile(sw, accA[0][1], accA[1][1], 1, wBaseW);
    sbar();
    bf16x8 af0[2]; readA(sw, aBase, af0);
    sbar();
    *(unsigned long long*)(sw + zOff)      = 0ull;
    *(unsigned long long*)(sw + zOff + 8u) = 0ull;
    writeTile(sw, accA[0][2], accA[1][2], 0, wBaseW);
    sbar();
    bf16x8 af1[2]; readA(sw, aBase, af1);

    f32x4 acc8[2] = {b8v, b8v};
#pragma unroll
    for (int kt = 0; kt < 4; ++kt) {
      sbar();
#pragma unroll
      for (int c = 0; c < 2; ++c) {
        int nt = 2*kt + c;
        bf16x8 wfull = *(const bf16x8*)(smem + OFF_W7 + (unsigned)nt*1024u + bOff);
        bf16x8 whalf = *(const bf16x8*)(smem + OFF_W7 + 8192u + (unsigned)nt*512u + hOff);
        f32x4 bi = biasFrag(sB, 368, nt, g);     // b7
        f32x4 t0 = mfma16(whalf, af1[0], mfma16(wfull, af0[0], bi));
        f32x4 t1 = mfma16(whalf, af1[1], mfma16(wfull, af0[1], bi));
        writeTile(sw, t0, t1, c, wBaseW);
      }
      sbar();
      bf16x8 af8[2]; readA(sw, aBase, af8);
      acc8[0] = mfma16(w8f[kt], af8[0], acc8[0]);
      acc8[1] = mfma16(w8f[kt], af8[1], acc8[1]);
    }

    // ---- store fp32 output: lane (g==0, colId) owns row base+rt*16+colId, 3 floats ----
    if (g == 0) {
#pragma unroll
      for (int rt = 0; rt < 2; ++rt) {
        int row = base + rt*16 + colId;
        if (row < N) {
          size_t o = (size_t)row*3u;
          out[o+0] = acc8[rt][0];
          out[o+1] = acc8[rt][1];
          out[o+2] = acc8[rt][2];
        }
      }
    }

    // rotate prefetched inputs
#pragma unroll
    for (int rt = 0; rt < 2; ++rt)
#pragma unroll
      for (int j = 0; j < 6; ++j) inC[rt][j] = inN[rt][j];
  }
}

extern "C" void kernel_launch(void* const* d_in, const int* in_sizes, int n_in,
                              void* d_out, int out_size, void* d_ws, size_t ws_size,
                              hipStream_t stream) {
  const float* dims = (const float*)d_in[0];
  const float* xyz  = (const float*)d_in[1];
  const float* W1 = (const float*)d_in[2];  const float* b1 = (const float*)d_in[3];
  const float* W2 = (const float*)d_in[4];  const float* b2 = (const float*)d_in[5];
  const float* W3 = (const float*)d_in[6];  const float* b3 = (const float*)d_in[7];
  const float* W4 = (const float*)d_in[8];  const float* b4 = (const float*)d_in[9];
  const float* W5 = (const float*)d_in[10]; const float* b5 = (const float*)d_in[11];
  const float* W6 = (const float*)d_in[12]; const float* b6 = (const float*)d_in[13];
  const float* W7 = (const float*)d_in[14]; const float* b7 = (const float*)d_in[15];
  const float* W8 = (const float*)d_in[16]; const float* b8 = (const float*)d_in[17];
  float* out = (float*)d_out;
  const int N = in_sizes[0] / 3;

  pinn_mlp_kernel<<<dim3(512), dim3(BLOCK), 0, stream>>>(
      dims, xyz, W1, b1, W2, b2, W3, b3, W4, b4, W5, b5, W6, b6, W7, b7, W8, b8,
      out, N);
}